// Round 10
// baseline (601.407 us; speedup 1.0000x reference)
//
#include <hip/hip_runtime.h>
#include <hip/hip_fp16.h>

// r17: resubmit of r16 (packed-fp16 quad-GAT) — r16 died at GPU acquisition
// (infra), no on-GPU verdict. Source unchanged; re-audited: vbuf packing,
// alignment, pad-zeroing, stats reduction all ok.
// Levers: halve VALU work (v_pk_fma_f16 for el-dot/acc/epilogue) and halve
// acc VGPRs -> more resident waves. den/exp/LN stay fp32.

#define NN 10000
#define BB 32
#define EE 40000
#define HH 4
#define DD 10
#define TT 10
#define NEG 0.2f

#define NB   (NN*BB)          // 320000
#define NBT  (NN*BB*TT)       // 3200000
#define RH   16               // halves per feat row (10 + 6 pad, 32B)

__device__ __forceinline__ __half2 u2h(unsigned u) {
    return *reinterpret_cast<const __half2*>(&u);
}

__device__ __forceinline__ void load_row_h2(const __half* p, __half2 (&fr)[5]) {
    uint4 a = *(const uint4*)p;
    unsigned e = *((const unsigned*)p + 4);
    fr[0] = u2h(a.x); fr[1] = u2h(a.y); fr[2] = u2h(a.z); fr[3] = u2h(a.w); fr[4] = u2h(e);
}

// ---------------- extract mu/sigma (fp16 rows) + regression ---------------
__global__ void extract_kernel(const float* __restrict__ x,
                               const float* __restrict__ wmu, const float* __restrict__ bmu,
                               const float* __restrict__ wsg, const float* __restrict__ bsg,
                               __half* __restrict__ muH, __half* __restrict__ sgH,
                               float* __restrict__ regmu, float* __restrict__ regsg) {
    int i = blockIdx.x * blockDim.x + threadIdx.x;   // over N*B
    if (i >= NB) return;
    int n = i / BB, b = i % BB;
    float smu = 0.f, ssg = 0.f;
    float muv[TT], sgv[TT];
#pragma unroll
    for (int t = 0; t < TT; t++) {
        size_t xi = (((size_t)t * NN + n) * BB + b) * 3;
        float m = x[xi], s = x[xi + 1];
        muv[t] = m; sgv[t] = s;
        smu += m * wmu[t];
        ssg += s * wsg[t];
    }
    __half2* dm = (__half2*)(muH + (size_t)i * RH);
    __half2* ds = (__half2*)(sgH + (size_t)i * RH);
    __half2 z = __floats2half2_rn(0.f, 0.f);
#pragma unroll
    for (int j = 0; j < 5; j++) {
        dm[j] = __floats2half2_rn(muv[2 * j], muv[2 * j + 1]);
        ds[j] = __floats2half2_rn(sgv[2 * j], sgv[2 * j + 1]);
    }
    dm[5] = z; dm[6] = z; dm[7] = z;
    ds[5] = z; ds[6] = z; ds[7] = z;
    regmu[i] = smu + bmu[0];
    regsg[i] = ssg + bsg[0];
}

// ---------------- CSR build (both graphs in one dispatch) ----------------
__global__ void deg2_kernel(const int* __restrict__ dst0, int* __restrict__ deg0,
                            const int* __restrict__ dst1, int* __restrict__ deg1) {
    int e = blockIdx.x * blockDim.x + threadIdx.x;
    const int* dst = blockIdx.y ? dst1 : dst0;
    int* deg       = blockIdx.y ? deg1 : deg0;
    if (e < EE) atomicAdd(&deg[dst[e]], 1);
}

__global__ void scan2_kernel(const int* __restrict__ deg0, int* __restrict__ off0,
                             const int* __restrict__ deg1, int* __restrict__ off1) {
    const int* __restrict__ deg = blockIdx.x ? deg1 : deg0;
    int* __restrict__ off       = blockIdx.x ? off1 : off0;
    __shared__ int sm[16];
    __shared__ int carry_s;
    int tid = threadIdx.x;               // 1024 threads = 16 waves
    int lane = tid & 63, wid = tid >> 6;
    if (tid == 0) { carry_s = 0; off[0] = 0; }
    __syncthreads();
    for (int base = 0; base < NN; base += 1024) {
        int i = base + tid;
        int v = (i < NN) ? deg[i] : 0;
        int x = v;
#pragma unroll
        for (int s = 1; s < 64; s <<= 1) {
            int t = __shfl_up(x, s, 64);
            if (lane >= s) x += t;
        }
        if (lane == 63) sm[wid] = x;
        __syncthreads();
        if (wid == 0) {
            int w = (lane < 16) ? sm[lane] : 0;
#pragma unroll
            for (int s = 1; s < 16; s <<= 1) {
                int t = __shfl_up(w, s, 64);
                if (lane >= s) w += t;
            }
            if (lane < 16) sm[lane] = w;
        }
        __syncthreads();
        int add = carry_s + ((wid > 0) ? sm[wid - 1] : 0);
        if (i < NN) off[i + 1] = add + x;
        int total = sm[15];
        __syncthreads();
        if (tid == 0) carry_s += total;
        __syncthreads();
    }
}

__global__ void fill2_kernel(const int* __restrict__ src0, const int* __restrict__ dst0,
                             const int* __restrict__ off0, int* __restrict__ cur0,
                             int* __restrict__ csr0,
                             const int* __restrict__ src1, const int* __restrict__ dst1,
                             const int* __restrict__ off1, int* __restrict__ cur1,
                             int* __restrict__ csr1) {
    int e = blockIdx.x * blockDim.x + threadIdx.x;
    const int* src = blockIdx.y ? src1 : src0;
    const int* dst = blockIdx.y ? dst1 : dst0;
    const int* off = blockIdx.y ? off1 : off0;
    int* cursor    = blockIdx.y ? cur1 : cur0;
    int* csr       = blockIdx.y ? csr1 : csr0;
    if (e < EE) {
        int d = dst[e];
        int p = atomicAdd(&cursor[d], 1);
        csr[off[d] + p] = src[e];
    }
}

// ---------------- degree sort: counting sort into perm (descending deg) ---
__global__ void hist2_kernel(const int* __restrict__ deg0, const int* __restrict__ deg1,
                             int* __restrict__ hist) {
    __shared__ int lh[64];
    if (threadIdx.x < 64) lh[threadIdx.x] = 0;
    __syncthreads();
    int n = blockIdx.x * blockDim.x + threadIdx.x;
    int g = blockIdx.y;
    const int* deg = g ? deg1 : deg0;
    if (n < NN) {
        int d = deg[n];
        int bin = 63 - ((d < 63) ? d : 63);
        atomicAdd(&lh[bin], 1);
    }
    __syncthreads();
    if (threadIdx.x < 64 && lh[threadIdx.x])
        atomicAdd(&hist[g * 64 + threadIdx.x], lh[threadIdx.x]);
}

__global__ void binoff_kernel(const int* __restrict__ hist, int* __restrict__ boff) {
    int g = threadIdx.x >> 6, lane = threadIdx.x & 63;
    int v = hist[g * 64 + lane];
    int x = v;
#pragma unroll
    for (int s = 1; s < 64; s <<= 1) {
        int t = __shfl_up(x, s, 64);
        if (lane >= s) x += t;
    }
    boff[g * 64 + lane] = x - v;
}

__global__ void permfill2_kernel(const int* __restrict__ deg0, const int* __restrict__ deg1,
                                 const int* __restrict__ boff, int* __restrict__ bcur,
                                 int* __restrict__ perm0, int* __restrict__ perm1) {
    __shared__ int lh[64], lbase[64];
    if (threadIdx.x < 64) lh[threadIdx.x] = 0;
    __syncthreads();
    int n = blockIdx.x * blockDim.x + threadIdx.x;
    int g = blockIdx.y;
    const int* deg = g ? deg1 : deg0;
    int* perm      = g ? perm1 : perm0;
    int bin = 0, myp = 0;
    if (n < NN) {
        int d = deg[n];
        bin = 63 - ((d < 63) ? d : 63);
        myp = atomicAdd(&lh[bin], 1);
    }
    __syncthreads();
    if (threadIdx.x < 64) {
        int c = lh[threadIdx.x];
        lbase[threadIdx.x] = c ? atomicAdd(&bcur[g * 64 + threadIdx.x], c) : 0;
    }
    __syncthreads();
    if (n < NN) perm[boff[g * 64 + bin] + lbase[bin] + myp] = n;
}

// ---------------- precompute vl/vr (fp16) for all 8 GATs ------------------
__global__ void vpre_kernel(const float* __restrict__ fc0, const float* __restrict__ al0, const float* __restrict__ ar0,
                            const float* __restrict__ fc1, const float* __restrict__ al1, const float* __restrict__ ar1,
                            const float* __restrict__ fc2, const float* __restrict__ al2, const float* __restrict__ ar2,
                            const float* __restrict__ fc3, const float* __restrict__ al3, const float* __restrict__ ar3,
                            __half* __restrict__ vbufH) {
    int j = threadIdx.x;                 // 0..319
    if (j >= 320) return;
    int g = j / 40, r = j % 40;
    int h = r / 10, t = r % 10;
    int which = g & 3, layer = g >> 2;
    const float* fc; const float* al; const float* ar;
    if (which == 0)      { fc = fc0; al = al0; ar = ar0; }
    else if (which == 1) { fc = fc1; al = al1; ar = ar1; }
    else if (which == 2) { fc = fc2; al = al2; ar = ar2; }
    else                 { fc = fc3; al = al3; ar = ar3; }
    fc += layer * (HH * DD * TT);
    al += layer * (HH * DD);
    ar += layer * (HH * DD);
    float vl = 0.f, vr = 0.f;
#pragma unroll
    for (int d = 0; d < DD; d++) {
        float w = fc[(h * DD + d) * TT + t];
        vl += al[h * DD + d] * w;
        vr += ar[h * DD + d] * w;
    }
    vbufH[g * 80 + h * 10 + t]      = __float2half(vl);
    vbufH[g * 80 + 40 + h * 10 + t] = __float2half(vr);
}

// ---------------- quad-GAT, packed fp16 math ------------------------------
struct QCfg {
    const __half* f;       // 16-half rows
    const float* W;        // [H*D][T] fp32
    const __half* v;       // vl[40] | vr[40] halves
    const int* off; const int* csr; const int* perm;
    float* g; float* stats;
};
struct QCfg4 { QCfg c[4]; };

__device__ __forceinline__ void edge_h2(const __half2 (&fr)[5], bool val,
                                        const uint (&vl)[HH][5],
                                        const float (&er)[HH],
                                        float (&den)[HH], __half2 (&acc)[HH][5]) {
#pragma unroll
    for (int h = 0; h < HH; h++) {
        __half2 z2 = __hmul2(u2h(vl[h][0]), fr[0]);
#pragma unroll
        for (int j = 1; j < 5; j++) z2 = __hfma2(u2h(vl[h][j]), fr[j], z2);
        float z = __low2float(z2) + __high2float(z2) + er[h];
        z = (z >= 0.f) ? z : NEG * z;
        float w = val ? __expf(z) : 0.f;
        den[h] += w;
        __half2 w2 = __float2half2_rn(w);
#pragma unroll
        for (int j = 0; j < 5; j++) acc[h][j] = __hfma2(w2, fr[j], acc[h][j]);
    }
}

template <bool STATS>
__global__ void __launch_bounds__(256, 6)
gatq_kernel(QCfg4 cfgs) {
    const QCfg cfg = cfgs.c[blockIdx.y];
    __shared__ __align__(16) __half sW[HH * DD * 16];   // rows padded to 16 halves
    for (int kk = threadIdx.x; kk < HH * DD * 16; kk += blockDim.x)
        sW[kk] = __float2half(0.f);
    __syncthreads();
    for (int kk = threadIdx.x; kk < HH * DD * TT; kk += blockDim.x) {
        int r = kk / TT, t = kk - r * TT;
        sW[r * 16 + t] = __float2half(cfg.W[kk]);
    }
    __syncthreads();

    const __half* __restrict__ f = cfg.f;
    const int* __restrict__ csr  = cfg.csr;
    const uint* __restrict__ vu  = (const uint*)cfg.v;   // wave-uniform -> SGPR

    int i = blockIdx.x * blockDim.x + threadIdx.x;   // over NB
    float lsum = 0.f, lsq = 0.f;
    if (i < NB) {
        int b = i & 31;
        int slot = i >> 5;
        int n = cfg.perm[slot];
        int nb = n * BB + b;
        int s0 = cfg.off[n], s1 = cfg.off[n + 1];

        uint vl[HH][5], vr[HH][5];
#pragma unroll
        for (int h = 0; h < HH; h++)
#pragma unroll
            for (int j = 0; j < 5; j++) {
                vl[h][j] = vu[h * 5 + j];
                vr[h][j] = vu[20 + h * 5 + j];
            }

        // er from self row (packed dot)
        float er[HH];
        {
            __half2 fs[5];
            load_row_h2(f + (size_t)nb * RH, fs);
#pragma unroll
            for (int h = 0; h < HH; h++) {
                __half2 z2 = __hmul2(u2h(vr[h][0]), fs[0]);
#pragma unroll
                for (int j = 1; j < 5; j++) z2 = __hfma2(u2h(vr[h][j]), fs[j], z2);
                er[h] = __low2float(z2) + __high2float(z2);
            }
        }

        __half2 acc[HH][5];
        float den[HH];
        __half2 zz = __floats2half2_rn(0.f, 0.f);
#pragma unroll
        for (int h = 0; h < HH; h++) {
            den[h] = 0.f;
#pragma unroll
            for (int j = 0; j < 5; j++) acc[h][j] = zz;
        }

        for (int k = s0; k < s1; k += 2) {
            int kb = (k + 1 < s1) ? k + 1 : s0;
            bool v1 = (k + 1 < s1);
            int e0 = csr[k], e1 = csr[kb];
            __half2 fr0[5], fr1[5];
            load_row_h2(f + (size_t)(e0 * BB + b) * RH, fr0);
            load_row_h2(f + (size_t)(e1 * BB + b) * RH, fr1);
            edge_h2(fr0, true, vl, er, den, acc);
            edge_h2(fr1, v1,   vl, er, den, acc);
        }

        bool nz = (s1 > s0);
        float outv[DD];
#pragma unroll
        for (int d = 0; d < DD; d++) outv[d] = 0.f;
#pragma unroll
        for (int h = 0; h < HH; h++) {
            float rd = nz ? (1.0f / den[h]) : 0.f;
#pragma unroll
            for (int d = 0; d < DD; d++) {
                const __half2* wr = (const __half2*)&sW[(h * DD + d) * 16];
                __half2 y2 = __hmul2(wr[0], acc[h][0]);
#pragma unroll
                for (int j = 1; j < 5; j++) y2 = __hfma2(wr[j], acc[h][j], y2);
                float y = (__low2float(y2) + __high2float(y2)) * rd;
                y = (y >= 0.f) ? y : NEG * y;
                outv[d] += 0.25f * y;
            }
        }

        float* gp = cfg.g + (size_t)nb * DD;
        *(float4*)gp       = make_float4(outv[0], outv[1], outv[2], outv[3]);
        *(float4*)(gp + 4) = make_float4(outv[4], outv[5], outv[6], outv[7]);
        *(float2*)(gp + 8) = make_float2(outv[8], outv[9]);
        if (STATS) {
#pragma unroll
            for (int d = 0; d < DD; d++) { lsum += outv[d]; lsq += outv[d] * outv[d]; }
        }
    }
    if (STATS) {
#pragma unroll
        for (int o = 32; o > 0; o >>= 1) {
            lsum += __shfl_down(lsum, o, 64);
            lsq  += __shfl_down(lsq, o, 64);
        }
        __shared__ float ss[4][2];
        int wid = threadIdx.x >> 6, lid = threadIdx.x & 63;
        if (lid == 0) { ss[wid][0] = lsum; ss[wid][1] = lsq; }
        __syncthreads();
        if (threadIdx.x == 0) {
            float a0 = 0.f, a1 = 0.f;
#pragma unroll
            for (int w = 0; w < 4; w++) { a0 += ss[w][0]; a1 += ss[w][1]; }
            atomicAdd(&cfg.stats[0], a0);
            atomicAdd(&cfg.stats[1], a1);
        }
    }
}

// ---------------- LN(A), LN(B), average; writes fp16 16-half rows ---------
__global__ void lncomb2_kernel(const float* __restrict__ gA, const float* __restrict__ gB,
                               const float* __restrict__ gA2, const float* __restrict__ gB2,
                               const float* __restrict__ stats,
                               __half* __restrict__ hp, __half* __restrict__ hrl) {
    int i = blockIdx.x * blockDim.x + threadIdx.x;   // over NB*8 half2-slots
    if (i >= NB * 8) return;
    const float* ga = blockIdx.y ? gA2 : gA;
    const float* gb = blockIdx.y ? gB2 : gB;
    const float* st = stats + (blockIdx.y ? 4 : 0);
    __half2* h      = (__half2*)(blockIdx.y ? hrl : hp);
    int nb = i >> 3, t2 = i & 7;
    float v0 = 0.f, v1 = 0.f;
    if (t2 < 5) {
        const float M = (float)NBT;
        float ma = st[0] / M; float va = st[1] / M - ma * ma;
        float mb = st[2] / M; float vb = st[3] / M - mb * mb;
        float ra = rsqrtf(va + 1e-5f), rb = rsqrtf(vb + 1e-5f);
        size_t base = (size_t)nb * DD + t2 * 2;
        v0 = 0.5f * ((ga[base] - ma) * ra + (gb[base] - mb) * rb);
        v1 = 0.5f * ((ga[base + 1] - ma) * ra + (gb[base + 1] - mb) * rb);
    }
    h[(size_t)nb * 8 + t2] = __floats2half2_rn(v0, v1);
}

// ---------------- final combine, both outputs in one dispatch -------------
__global__ void outcomb2_kernel(const float* __restrict__ regmu, const float* __restrict__ regsg,
                                const float* __restrict__ gA, const float* __restrict__ gA2,
                                const float* __restrict__ gB, const float* __restrict__ gB2,
                                float* __restrict__ out) {
    int i = blockIdx.x * blockDim.x + threadIdx.x;
    if (i >= NBT) return;
    int nb = i / DD;
    if (blockIdx.y == 0) out[i]       = (regmu[nb] + gA[i] + gA2[i]) * (1.0f / 3.0f);
    else                 out[NBT + i] = (regsg[nb] + gB[i] + gB2[i]) * (1.0f / 3.0f);
}

extern "C" void kernel_launch(void* const* d_in, const int* in_sizes, int n_in,
                              void* d_out, int out_size, void* d_ws, size_t ws_size,
                              hipStream_t stream) {
    const float* x      = (const float*)d_in[0];
    const int* ps_src   = (const int*)d_in[1];
    const int* ps_dst   = (const int*)d_in[2];
    const int* rl_src   = (const int*)d_in[3];
    const int* rl_dst   = (const int*)d_in[4];
    const float* mu_p_fc = (const float*)d_in[5];
    const float* mu_p_al = (const float*)d_in[6];
    const float* mu_p_ar = (const float*)d_in[7];
    const float* sg_p_fc = (const float*)d_in[8];
    const float* sg_p_al = (const float*)d_in[9];
    const float* sg_p_ar = (const float*)d_in[10];
    const float* mu_r_fc = (const float*)d_in[11];
    const float* mu_r_al = (const float*)d_in[12];
    const float* mu_r_ar = (const float*)d_in[13];
    const float* sg_r_fc = (const float*)d_in[14];
    const float* sg_r_al = (const float*)d_in[15];
    const float* sg_r_ar = (const float*)d_in[16];
    const float* reg_mu_w = (const float*)d_in[17];
    const float* reg_mu_b = (const float*)d_in[18];
    const float* reg_sg_w = (const float*)d_in[19];
    const float* reg_sg_b = (const float*)d_in[20];

    float* out = (float*)d_out;

    // ---- workspace carve (counts in floats) ----
    float* fw = (float*)d_ws;
    __half* muH  = (__half*)fw;     fw += NB * 8;    // 16 halves/row
    __half* sgH  = (__half*)fw;     fw += NB * 8;
    __half* hpH  = (__half*)fw;     fw += NB * 8;
    __half* hrlH = (__half*)fw;     fw += NB * 8;
    float* gA    = fw;              fw += NBT;       // fp32 GAT outputs, stride 10
    float* gB    = fw;              fw += NBT;
    float* gA2   = fw;              fw += NBT;
    float* gB2   = fw;              fw += NBT;
    float* regmu = fw;              fw += NB;
    float* regsg = fw;              fw += NB;
    __half* vbufH = (__half*)fw;    fw += 8 * 40;    // 8 slots x 80 halves
    int* iw = (int*)fw;
    int* ps_off = iw;               iw += NN + 1;
    int* rl_off = iw;               iw += NN + 1;
    int* ps_csr = iw;               iw += EE;
    int* rl_csr = iw;               iw += EE;
    int* perm_ps = iw;              iw += NN;
    int* perm_rl = iw;              iw += NN;
    int* boff   = iw;               iw += 128;
    // zero region starts here:
    int* deg_ps = iw;               iw += NN;
    int* cur_ps = iw;               iw += NN;
    int* deg_rl = iw;               iw += NN;
    int* cur_rl = iw;               iw += NN;
    int* hist   = iw;               iw += 128;
    int* bcur   = iw;               iw += 128;
    float* stats = (float*)iw;      // 8 floats
    size_t zero_bytes = (size_t)(4 * NN + 256) * sizeof(int) + 8 * sizeof(float);
    hipMemsetAsync(deg_ps, 0, zero_bytes, stream);

    const int TPB = 256;
    const int GRID_NB  = (NB + TPB - 1) / TPB;          // 1250
    const int GRID_NBT = (NBT + TPB - 1) / TPB;
    const int GRID_LN  = (NB * 8 + TPB - 1) / TPB;      // 10000
    const int GRID_E   = (EE + TPB - 1) / TPB;
    const int GRID_N   = (NN + TPB - 1) / TPB;          // 40

    extract_kernel<<<GRID_NB, TPB, 0, stream>>>(x, reg_mu_w, reg_mu_b, reg_sg_w, reg_sg_b,
                                                muH, sgH, regmu, regsg);

    // CSR + degree-sort for both graphs
    {
        dim3 g(GRID_E, 2, 1);
        dim3 gn(GRID_N, 2, 1);
        deg2_kernel<<<g, TPB, 0, stream>>>(ps_dst, deg_ps, rl_dst, deg_rl);
        scan2_kernel<<<2, 1024, 0, stream>>>(deg_ps, ps_off, deg_rl, rl_off);
        fill2_kernel<<<g, TPB, 0, stream>>>(ps_src, ps_dst, ps_off, cur_ps, ps_csr,
                                            rl_src, rl_dst, rl_off, cur_rl, rl_csr);
        hist2_kernel<<<gn, TPB, 0, stream>>>(deg_ps, deg_rl, hist);
        binoff_kernel<<<1, 128, 0, stream>>>(hist, boff);
        permfill2_kernel<<<gn, TPB, 0, stream>>>(deg_ps, deg_rl, boff, bcur, perm_ps, perm_rl);
    }

    vpre_kernel<<<1, 320, 0, stream>>>(mu_p_fc, mu_p_al, mu_p_ar,
                                       sg_p_fc, sg_p_al, sg_p_ar,
                                       mu_r_fc, mu_r_al, mu_r_ar,
                                       sg_r_fc, sg_r_al, sg_r_ar, vbufH);

    // slots: 0 mu_p L0, 1 sg_p L0, 2 mu_r L0, 3 sg_r L0, 4..7 = L1
    // ---- layer 0: 4 GATs in one dispatch ----
    {
        QCfg4 c;
        c.c[0] = { muH, mu_p_fc,       vbufH + 0 * 80, ps_off, ps_csr, perm_ps, gA,  stats + 0 };
        c.c[1] = { sgH, sg_p_fc,       vbufH + 1 * 80, ps_off, ps_csr, perm_ps, gB,  stats + 2 };
        c.c[2] = { muH, mu_r_fc,       vbufH + 2 * 80, rl_off, rl_csr, perm_rl, gA2, stats + 4 };
        c.c[3] = { sgH, sg_r_fc,       vbufH + 3 * 80, rl_off, rl_csr, perm_rl, gB2, stats + 6 };
        dim3 grid(GRID_NB, 4, 1);
        gatq_kernel<true><<<grid, TPB, 0, stream>>>(c);
    }
    {
        dim3 g(GRID_LN, 2, 1);
        lncomb2_kernel<<<g, TPB, 0, stream>>>(gA, gB, gA2, gB2, stats, hpH, hrlH);
    }

    // ---- final layers: 4 GATs in one dispatch ----
    {
        QCfg4 c;
        c.c[0] = { hpH,  mu_p_fc + 400, vbufH + 4 * 80, ps_off, ps_csr, perm_ps, gA,  nullptr };
        c.c[1] = { hpH,  sg_p_fc + 400, vbufH + 5 * 80, ps_off, ps_csr, perm_ps, gB,  nullptr };
        c.c[2] = { hrlH, mu_r_fc + 400, vbufH + 6 * 80, rl_off, rl_csr, perm_rl, gA2, nullptr };
        c.c[3] = { hrlH, sg_r_fc + 400, vbufH + 7 * 80, rl_off, rl_csr, perm_rl, gB2, nullptr };
        dim3 grid(GRID_NB, 4, 1);
        gatq_kernel<false><<<grid, TPB, 0, stream>>>(c);
    }

    {
        dim3 g(GRID_NBT, 2, 1);
        outcomb2_kernel<<<g, TPB, 0, stream>>>(regmu, regsg, gA, gA2, gB, gB2, out);
    }
}

// Round 15
// 397.400 us; speedup vs baseline: 1.5134x; 1.5134x over previous
//
#include <hip/hip_runtime.h>
#include <hip/hip_fp16.h>

// r22: fifth submission of the spill-fixed packed-fp16 quad-GAT (r18-r21 all
// died on infra; error classes previously resolved on identical resubmits,
// and r17 — same kernel family/size — ran fine at round 10, so failures are
// host contention, not source).
// r17's launch_bounds(256,6) capped VGPR -> allocator spilled per-edge state
// -> 570MB scratch writes/dispatch (measured). Fix: plain launch_bounds(256);
// vl/vr forced to SGPR via readfirstlane hoisted above the divergent branch.

#define NN 10000
#define BB 32
#define EE 40000
#define HH 4
#define DD 10
#define TT 10
#define NEG 0.2f

#define NB   (NN*BB)          // 320000
#define NBT  (NN*BB*TT)       // 3200000
#define RH   16               // halves per feat row (10 + 6 pad, 32B)

__device__ __forceinline__ __half2 u2h(unsigned u) {
    return *reinterpret_cast<const __half2*>(&u);
}

__device__ __forceinline__ void load_row_h2(const __half* p, __half2 (&fr)[5]) {
    uint4 a = *(const uint4*)p;
    unsigned e = *((const unsigned*)p + 4);
    fr[0] = u2h(a.x); fr[1] = u2h(a.y); fr[2] = u2h(a.z); fr[3] = u2h(a.w); fr[4] = u2h(e);
}

// ---------------- extract mu/sigma (fp16 rows) + regression ---------------
__global__ void extract_kernel(const float* __restrict__ x,
                               const float* __restrict__ wmu, const float* __restrict__ bmu,
                               const float* __restrict__ wsg, const float* __restrict__ bsg,
                               __half* __restrict__ muH, __half* __restrict__ sgH,
                               float* __restrict__ regmu, float* __restrict__ regsg) {
    int i = blockIdx.x * blockDim.x + threadIdx.x;   // over N*B
    if (i >= NB) return;
    int n = i / BB, b = i % BB;
    float smu = 0.f, ssg = 0.f;
    float muv[TT], sgv[TT];
#pragma unroll
    for (int t = 0; t < TT; t++) {
        size_t xi = (((size_t)t * NN + n) * BB + b) * 3;
        float m = x[xi], s = x[xi + 1];
        muv[t] = m; sgv[t] = s;
        smu += m * wmu[t];
        ssg += s * wsg[t];
    }
    __half2* dm = (__half2*)(muH + (size_t)i * RH);
    __half2* ds = (__half2*)(sgH + (size_t)i * RH);
    __half2 z = __floats2half2_rn(0.f, 0.f);
#pragma unroll
    for (int j = 0; j < 5; j++) {
        dm[j] = __floats2half2_rn(muv[2 * j], muv[2 * j + 1]);
        ds[j] = __floats2half2_rn(sgv[2 * j], sgv[2 * j + 1]);
    }
    dm[5] = z; dm[6] = z; dm[7] = z;
    ds[5] = z; ds[6] = z; ds[7] = z;
    regmu[i] = smu + bmu[0];
    regsg[i] = ssg + bsg[0];
}

// ---------------- CSR build (both graphs in one dispatch) ----------------
__global__ void deg2_kernel(const int* __restrict__ dst0, int* __restrict__ deg0,
                            const int* __restrict__ dst1, int* __restrict__ deg1) {
    int e = blockIdx.x * blockDim.x + threadIdx.x;
    const int* dst = blockIdx.y ? dst1 : dst0;
    int* deg       = blockIdx.y ? deg1 : deg0;
    if (e < EE) atomicAdd(&deg[dst[e]], 1);
}

__global__ void scan2_kernel(const int* __restrict__ deg0, int* __restrict__ off0,
                             const int* __restrict__ deg1, int* __restrict__ off1) {
    const int* __restrict__ deg = blockIdx.x ? deg1 : deg0;
    int* __restrict__ off       = blockIdx.x ? off1 : off0;
    __shared__ int sm[16];
    __shared__ int carry_s;
    int tid = threadIdx.x;               // 1024 threads = 16 waves
    int lane = tid & 63, wid = tid >> 6;
    if (tid == 0) { carry_s = 0; off[0] = 0; }
    __syncthreads();
    for (int base = 0; base < NN; base += 1024) {
        int i = base + tid;
        int v = (i < NN) ? deg[i] : 0;
        int x = v;
#pragma unroll
        for (int s = 1; s < 64; s <<= 1) {
            int t = __shfl_up(x, s, 64);
            if (lane >= s) x += t;
        }
        if (lane == 63) sm[wid] = x;
        __syncthreads();
        if (wid == 0) {
            int w = (lane < 16) ? sm[lane] : 0;
#pragma unroll
            for (int s = 1; s < 16; s <<= 1) {
                int t = __shfl_up(w, s, 64);
                if (lane >= s) w += t;
            }
            if (lane < 16) sm[lane] = w;
        }
        __syncthreads();
        int add = carry_s + ((wid > 0) ? sm[wid - 1] : 0);
        if (i < NN) off[i + 1] = add + x;
        int total = sm[15];
        __syncthreads();
        if (tid == 0) carry_s += total;
        __syncthreads();
    }
}

__global__ void fill2_kernel(const int* __restrict__ src0, const int* __restrict__ dst0,
                             const int* __restrict__ off0, int* __restrict__ cur0,
                             int* __restrict__ csr0,
                             const int* __restrict__ src1, const int* __restrict__ dst1,
                             const int* __restrict__ off1, int* __restrict__ cur1,
                             int* __restrict__ csr1) {
    int e = blockIdx.x * blockDim.x + threadIdx.x;
    const int* src = blockIdx.y ? src1 : src0;
    const int* dst = blockIdx.y ? dst1 : dst0;
    const int* off = blockIdx.y ? off1 : off0;
    int* cursor    = blockIdx.y ? cur1 : cur0;
    int* csr       = blockIdx.y ? csr1 : csr0;
    if (e < EE) {
        int d = dst[e];
        int p = atomicAdd(&cursor[d], 1);
        csr[off[d] + p] = src[e];
    }
}

// ---------------- degree sort: counting sort into perm (descending deg) ---
__global__ void hist2_kernel(const int* __restrict__ deg0, const int* __restrict__ deg1,
                             int* __restrict__ hist) {
    __shared__ int lh[64];
    if (threadIdx.x < 64) lh[threadIdx.x] = 0;
    __syncthreads();
    int n = blockIdx.x * blockDim.x + threadIdx.x;
    int g = blockIdx.y;
    const int* deg = g ? deg1 : deg0;
    if (n < NN) {
        int d = deg[n];
        int bin = 63 - ((d < 63) ? d : 63);
        atomicAdd(&lh[bin], 1);
    }
    __syncthreads();
    if (threadIdx.x < 64 && lh[threadIdx.x])
        atomicAdd(&hist[g * 64 + threadIdx.x], lh[threadIdx.x]);
}

__global__ void binoff_kernel(const int* __restrict__ hist, int* __restrict__ boff) {
    int g = threadIdx.x >> 6, lane = threadIdx.x & 63;
    int v = hist[g * 64 + lane];
    int x = v;
#pragma unroll
    for (int s = 1; s < 64; s <<= 1) {
        int t = __shfl_up(x, s, 64);
        if (lane >= s) x += t;
    }
    boff[g * 64 + lane] = x - v;
}

__global__ void permfill2_kernel(const int* __restrict__ deg0, const int* __restrict__ deg1,
                                 const int* __restrict__ boff, int* __restrict__ bcur,
                                 int* __restrict__ perm0, int* __restrict__ perm1) {
    __shared__ int lh[64], lbase[64];
    if (threadIdx.x < 64) lh[threadIdx.x] = 0;
    __syncthreads();
    int n = blockIdx.x * blockDim.x + threadIdx.x;
    int g = blockIdx.y;
    const int* deg = g ? deg1 : deg0;
    int* perm      = g ? perm1 : perm0;
    int bin = 0, myp = 0;
    if (n < NN) {
        int d = deg[n];
        bin = 63 - ((d < 63) ? d : 63);
        myp = atomicAdd(&lh[bin], 1);
    }
    __syncthreads();
    if (threadIdx.x < 64) {
        int c = lh[threadIdx.x];
        lbase[threadIdx.x] = c ? atomicAdd(&bcur[g * 64 + threadIdx.x], c) : 0;
    }
    __syncthreads();
    if (n < NN) perm[boff[g * 64 + bin] + lbase[bin] + myp] = n;
}

// ---------------- precompute vl/vr (fp16) for all 8 GATs ------------------
__global__ void vpre_kernel(const float* __restrict__ fc0, const float* __restrict__ al0, const float* __restrict__ ar0,
                            const float* __restrict__ fc1, const float* __restrict__ al1, const float* __restrict__ ar1,
                            const float* __restrict__ fc2, const float* __restrict__ al2, const float* __restrict__ ar2,
                            const float* __restrict__ fc3, const float* __restrict__ al3, const float* __restrict__ ar3,
                            __half* __restrict__ vbufH) {
    int j = threadIdx.x;                 // 0..319
    if (j >= 320) return;
    int g = j / 40, r = j % 40;
    int h = r / 10, t = r % 10;
    int which = g & 3, layer = g >> 2;
    const float* fc; const float* al; const float* ar;
    if (which == 0)      { fc = fc0; al = al0; ar = ar0; }
    else if (which == 1) { fc = fc1; al = al1; ar = ar1; }
    else if (which == 2) { fc = fc2; al = al2; ar = ar2; }
    else                 { fc = fc3; al = al3; ar = ar3; }
    fc += layer * (HH * DD * TT);
    al += layer * (HH * DD);
    ar += layer * (HH * DD);
    float vl = 0.f, vr = 0.f;
#pragma unroll
    for (int d = 0; d < DD; d++) {
        float w = fc[(h * DD + d) * TT + t];
        vl += al[h * DD + d] * w;
        vr += ar[h * DD + d] * w;
    }
    vbufH[g * 80 + h * 10 + t]      = __float2half(vl);
    vbufH[g * 80 + 40 + h * 10 + t] = __float2half(vr);
}

// ---------------- quad-GAT, packed fp16 math, SGPR attention vecs ---------
struct QCfg {
    const __half* f;       // 16-half rows
    const float* W;        // [H*D][T] fp32
    const __half* v;       // vl[40] | vr[40] halves
    const int* off; const int* csr; const int* perm;
    float* g; float* stats;
};
struct QCfg4 { QCfg c[4]; };

__device__ __forceinline__ void edge_h2(const __half2 (&fr)[5], bool val,
                                        const uint (&vlu)[40],
                                        const float (&er)[HH],
                                        float (&den)[HH], __half2 (&acc)[HH][5]) {
#pragma unroll
    for (int h = 0; h < HH; h++) {
        __half2 z2 = __hmul2(u2h(vlu[h * 5 + 0]), fr[0]);
#pragma unroll
        for (int j = 1; j < 5; j++) z2 = __hfma2(u2h(vlu[h * 5 + j]), fr[j], z2);
        float z = __low2float(z2) + __high2float(z2) + er[h];
        z = (z >= 0.f) ? z : NEG * z;
        float w = val ? __expf(z) : 0.f;
        den[h] += w;
        __half2 w2 = __float2half2_rn(w);
#pragma unroll
        for (int j = 0; j < 5; j++) acc[h][j] = __hfma2(w2, fr[j], acc[h][j]);
    }
}

template <bool STATS>
__global__ void __launch_bounds__(256)
gatq_kernel(QCfg4 cfgs) {
    const QCfg cfg = cfgs.c[blockIdx.y];
    __shared__ __align__(16) __half sW[HH * DD * 16];   // rows padded to 16 halves
    for (int kk = threadIdx.x; kk < HH * DD * 16; kk += blockDim.x)
        sW[kk] = __float2half(0.f);
    __syncthreads();
    for (int kk = threadIdx.x; kk < HH * DD * TT; kk += blockDim.x) {
        int r = kk / TT, t = kk - r * TT;
        sW[r * 16 + t] = __float2half(cfg.W[kk]);
    }
    __syncthreads();

    const __half* __restrict__ f = cfg.f;
    const int* __restrict__ csr  = cfg.csr;
    const uint* __restrict__ vu  = (const uint*)cfg.v;

    // hoisted above the divergent branch; all lanes load the same address ->
    // readfirstlane pins the 80 attention halves into 40 SGPRs (no VGPR cost).
    uint vlu[40];
#pragma unroll
    for (int j = 0; j < 40; j++) vlu[j] = __builtin_amdgcn_readfirstlane(vu[j]);

    int i = blockIdx.x * blockDim.x + threadIdx.x;   // over NB
    float lsum = 0.f, lsq = 0.f;
    if (i < NB) {
        int b = i & 31;
        int slot = i >> 5;
        int n = cfg.perm[slot];
        int nb = n * BB + b;
        int s0 = cfg.off[n], s1 = cfg.off[n + 1];

        // er from self row (packed dot with vr = vlu[20..39])
        float er[HH];
        {
            __half2 fs[5];
            load_row_h2(f + (size_t)nb * RH, fs);
#pragma unroll
            for (int h = 0; h < HH; h++) {
                __half2 z2 = __hmul2(u2h(vlu[20 + h * 5 + 0]), fs[0]);
#pragma unroll
                for (int j = 1; j < 5; j++) z2 = __hfma2(u2h(vlu[20 + h * 5 + j]), fs[j], z2);
                er[h] = __low2float(z2) + __high2float(z2);
            }
        }

        __half2 acc[HH][5];
        float den[HH];
        __half2 zz = __floats2half2_rn(0.f, 0.f);
#pragma unroll
        for (int h = 0; h < HH; h++) {
            den[h] = 0.f;
#pragma unroll
            for (int j = 0; j < 5; j++) acc[h][j] = zz;
        }

        for (int k = s0; k < s1; k += 2) {
            int kb = (k + 1 < s1) ? k + 1 : s0;
            bool v1 = (k + 1 < s1);
            int e0 = csr[k], e1 = csr[kb];
            __half2 fr0[5], fr1[5];
            load_row_h2(f + (size_t)(e0 * BB + b) * RH, fr0);
            load_row_h2(f + (size_t)(e1 * BB + b) * RH, fr1);
            edge_h2(fr0, true, vlu, er, den, acc);
            edge_h2(fr1, v1,   vlu, er, den, acc);
        }

        bool nz = (s1 > s0);
        float outv[DD];
#pragma unroll
        for (int d = 0; d < DD; d++) outv[d] = 0.f;
#pragma unroll
        for (int h = 0; h < HH; h++) {
            float rd = nz ? (1.0f / den[h]) : 0.f;
#pragma unroll
            for (int d = 0; d < DD; d++) {
                const __half2* wr = (const __half2*)&sW[(h * DD + d) * 16];
                __half2 y2 = __hmul2(wr[0], acc[h][0]);
#pragma unroll
                for (int j = 1; j < 5; j++) y2 = __hfma2(wr[j], acc[h][j], y2);
                float y = (__low2float(y2) + __high2float(y2)) * rd;
                y = (y >= 0.f) ? y : NEG * y;
                outv[d] += 0.25f * y;
            }
        }

        float* gp = cfg.g + (size_t)nb * DD;
        *(float4*)gp       = make_float4(outv[0], outv[1], outv[2], outv[3]);
        *(float4*)(gp + 4) = make_float4(outv[4], outv[5], outv[6], outv[7]);
        *(float2*)(gp + 8) = make_float2(outv[8], outv[9]);
        if (STATS) {
#pragma unroll
            for (int d = 0; d < DD; d++) { lsum += outv[d]; lsq += outv[d] * outv[d]; }
        }
    }
    if (STATS) {
#pragma unroll
        for (int o = 32; o > 0; o >>= 1) {
            lsum += __shfl_down(lsum, o, 64);
            lsq  += __shfl_down(lsq, o, 64);
        }
        __shared__ float ss[4][2];
        int wid = threadIdx.x >> 6, lid = threadIdx.x & 63;
        if (lid == 0) { ss[wid][0] = lsum; ss[wid][1] = lsq; }
        __syncthreads();
        if (threadIdx.x == 0) {
            float a0 = 0.f, a1 = 0.f;
#pragma unroll
            for (int w = 0; w < 4; w++) { a0 += ss[w][0]; a1 += ss[w][1]; }
            atomicAdd(&cfg.stats[0], a0);
            atomicAdd(&cfg.stats[1], a1);
        }
    }
}

// ---------------- LN(A), LN(B), average; writes fp16 16-half rows ---------
__global__ void lncomb2_kernel(const float* __restrict__ gA, const float* __restrict__ gB,
                               const float* __restrict__ gA2, const float* __restrict__ gB2,
                               const float* __restrict__ stats,
                               __half* __restrict__ hp, __half* __restrict__ hrl) {
    int i = blockIdx.x * blockDim.x + threadIdx.x;   // over NB*8 half2-slots
    if (i >= NB * 8) return;
    const float* ga = blockIdx.y ? gA2 : gA;
    const float* gb = blockIdx.y ? gB2 : gB;
    const float* st = stats + (blockIdx.y ? 4 : 0);
    __half2* h      = (__half2*)(blockIdx.y ? hrl : hp);
    int nb = i >> 3, t2 = i & 7;
    float v0 = 0.f, v1 = 0.f;
    if (t2 < 5) {
        const float M = (float)NBT;
        float ma = st[0] / M; float va = st[1] / M - ma * ma;
        float mb = st[2] / M; float vb = st[3] / M - mb * mb;
        float ra = rsqrtf(va + 1e-5f), rb = rsqrtf(vb + 1e-5f);
        size_t base = (size_t)nb * DD + t2 * 2;
        v0 = 0.5f * ((ga[base] - ma) * ra + (gb[base] - mb) * rb);
        v1 = 0.5f * ((ga[base + 1] - ma) * ra + (gb[base + 1] - mb) * rb);
    }
    h[(size_t)nb * 8 + t2] = __floats2half2_rn(v0, v1);
}

// ---------------- final combine, both outputs in one dispatch -------------
__global__ void outcomb2_kernel(const float* __restrict__ regmu, const float* __restrict__ regsg,
                                const float* __restrict__ gA, const float* __restrict__ gA2,
                                const float* __restrict__ gB, const float* __restrict__ gB2,
                                float* __restrict__ out) {
    int i = blockIdx.x * blockDim.x + threadIdx.x;
    if (i >= NBT) return;
    int nb = i / DD;
    if (blockIdx.y == 0) out[i]       = (regmu[nb] + gA[i] + gA2[i]) * (1.0f / 3.0f);
    else                 out[NBT + i] = (regsg[nb] + gB[i] + gB2[i]) * (1.0f / 3.0f);
}

extern "C" void kernel_launch(void* const* d_in, const int* in_sizes, int n_in,
                              void* d_out, int out_size, void* d_ws, size_t ws_size,
                              hipStream_t stream) {
    const float* x      = (const float*)d_in[0];
    const int* ps_src   = (const int*)d_in[1];
    const int* ps_dst   = (const int*)d_in[2];
    const int* rl_src   = (const int*)d_in[3];
    const int* rl_dst   = (const int*)d_in[4];
    const float* mu_p_fc = (const float*)d_in[5];
    const float* mu_p_al = (const float*)d_in[6];
    const float* mu_p_ar = (const float*)d_in[7];
    const float* sg_p_fc = (const float*)d_in[8];
    const float* sg_p_al = (const float*)d_in[9];
    const float* sg_p_ar = (const float*)d_in[10];
    const float* mu_r_fc = (const float*)d_in[11];
    const float* mu_r_al = (const float*)d_in[12];
    const float* mu_r_ar = (const float*)d_in[13];
    const float* sg_r_fc = (const float*)d_in[14];
    const float* sg_r_al = (const float*)d_in[15];
    const float* sg_r_ar = (const float*)d_in[16];
    const float* reg_mu_w = (const float*)d_in[17];
    const float* reg_mu_b = (const float*)d_in[18];
    const float* reg_sg_w = (const float*)d_in[19];
    const float* reg_sg_b = (const float*)d_in[20];

    float* out = (float*)d_out;

    // ---- workspace carve (counts in floats) ----
    float* fw = (float*)d_ws;
    __half* muH  = (__half*)fw;     fw += NB * 8;    // 16 halves/row
    __half* sgH  = (__half*)fw;     fw += NB * 8;
    __half* hpH  = (__half*)fw;     fw += NB * 8;
    __half* hrlH = (__half*)fw;     fw += NB * 8;
    float* gA    = fw;              fw += NBT;       // fp32 GAT outputs, stride 10
    float* gB    = fw;              fw += NBT;
    float* gA2   = fw;              fw += NBT;
    float* gB2   = fw;              fw += NBT;
    float* regmu = fw;              fw += NB;
    float* regsg = fw;              fw += NB;
    __half* vbufH = (__half*)fw;    fw += 8 * 40;    // 8 slots x 80 halves
    int* iw = (int*)fw;
    int* ps_off = iw;               iw += NN + 1;
    int* rl_off = iw;               iw += NN + 1;
    int* ps_csr = iw;               iw += EE;
    int* rl_csr = iw;               iw += EE;
    int* perm_ps = iw;              iw += NN;
    int* perm_rl = iw;              iw += NN;
    int* boff   = iw;               iw += 128;
    // zero region starts here:
    int* deg_ps = iw;               iw += NN;
    int* cur_ps = iw;               iw += NN;
    int* deg_rl = iw;               iw += NN;
    int* cur_rl = iw;               iw += NN;
    int* hist   = iw;               iw += 128;
    int* bcur   = iw;               iw += 128;
    float* stats = (float*)iw;      // 8 floats
    size_t zero_bytes = (size_t)(4 * NN + 256) * sizeof(int) + 8 * sizeof(float);
    hipMemsetAsync(deg_ps, 0, zero_bytes, stream);

    const int TPB = 256;
    const int GRID_NB  = (NB + TPB - 1) / TPB;          // 1250
    const int GRID_NBT = (NBT + TPB - 1) / TPB;
    const int GRID_LN  = (NB * 8 + TPB - 1) / TPB;      // 10000
    const int GRID_E   = (EE + TPB - 1) / TPB;
    const int GRID_N   = (NN + TPB - 1) / TPB;          // 40

    extract_kernel<<<GRID_NB, TPB, 0, stream>>>(x, reg_mu_w, reg_mu_b, reg_sg_w, reg_sg_b,
                                                muH, sgH, regmu, regsg);

    // CSR + degree-sort for both graphs
    {
        dim3 g(GRID_E, 2, 1);
        dim3 gn(GRID_N, 2, 1);
        deg2_kernel<<<g, TPB, 0, stream>>>(ps_dst, deg_ps, rl_dst, deg_rl);
        scan2_kernel<<<2, 1024, 0, stream>>>(deg_ps, ps_off, deg_rl, rl_off);
        fill2_kernel<<<g, TPB, 0, stream>>>(ps_src, ps_dst, ps_off, cur_ps, ps_csr,
                                            rl_src, rl_dst, rl_off, cur_rl, rl_csr);
        hist2_kernel<<<gn, TPB, 0, stream>>>(deg_ps, deg_rl, hist);
        binoff_kernel<<<1, 128, 0, stream>>>(hist, boff);
        permfill2_kernel<<<gn, TPB, 0, stream>>>(deg_ps, deg_rl, boff, bcur, perm_ps, perm_rl);
    }

    vpre_kernel<<<1, 320, 0, stream>>>(mu_p_fc, mu_p_al, mu_p_ar,
                                       sg_p_fc, sg_p_al, sg_p_ar,
                                       mu_r_fc, mu_r_al, mu_r_ar,
                                       sg_r_fc, sg_r_al, sg_r_ar, vbufH);

    // slots: 0 mu_p L0, 1 sg_p L0, 2 mu_r L0, 3 sg_r L0, 4..7 = L1
    // ---- layer 0: 4 GATs in one dispatch ----
    {
        QCfg4 c;
        c.c[0] = { muH, mu_p_fc,       vbufH + 0 * 80, ps_off, ps_csr, perm_ps, gA,  stats + 0 };
        c.c[1] = { sgH, sg_p_fc,       vbufH + 1 * 80, ps_off, ps_csr, perm_ps, gB,  stats + 2 };
        c.c[2] = { muH, mu_r_fc,       vbufH + 2 * 80, rl_off, rl_csr, perm_rl, gA2, stats + 4 };
        c.c[3] = { sgH, sg_r_fc,       vbufH + 3 * 80, rl_off, rl_csr, perm_rl, gB2, stats + 6 };
        dim3 grid(GRID_NB, 4, 1);
        gatq_kernel<true><<<grid, TPB, 0, stream>>>(c);
    }
    {
        dim3 g(GRID_LN, 2, 1);
        lncomb2_kernel<<<g, TPB, 0, stream>>>(gA, gB, gA2, gB2, stats, hpH, hrlH);
    }

    // ---- final layers: 4 GATs in one dispatch ----
    {
        QCfg4 c;
        c.c[0] = { hpH,  mu_p_fc + 400, vbufH + 4 * 80, ps_off, ps_csr, perm_ps, gA,  nullptr };
        c.c[1] = { hpH,  sg_p_fc + 400, vbufH + 5 * 80, ps_off, ps_csr, perm_ps, gB,  nullptr };
        c.c[2] = { hrlH, mu_r_fc + 400, vbufH + 6 * 80, rl_off, rl_csr, perm_rl, gA2, nullptr };
        c.c[3] = { hrlH, sg_r_fc + 400, vbufH + 7 * 80, rl_off, rl_csr, perm_rl, gB2, nullptr };
        dim3 grid(GRID_NB, 4, 1);
        gatq_kernel<false><<<grid, TPB, 0, stream>>>(c);
    }

    {
        dim3 g(GRID_NBT, 2, 1);
        outcomb2_kernel<<<g, TPB, 0, stream>>>(regmu, regsg, gA, gA2, gB, gB2, out);
    }
}